// Round 1
// 19298.419 us; speedup vs baseline: 1.1345x; 1.1345x over previous
//
#include <hip/hip_runtime.h>

// ---------------------------------------------------------------------------
// Persistent weight-stationary LSTM, bf16 MFMA, hand-rolled grid barrier.
// T=1024 B=64 C=256 H=512, 2 layers, fp32 in/out.
//  - 256 blocks x 256 threads, 1 block/CU, co-resident; blocks 0..127 = layer0
//    (step t), 128..255 = layer1 (step t-1) -> one grid barrier per tick.
//  - Weights bf16, packed once into MFMA B-frag order, held in VGPRs all run.
//    __launch_bounds__(256,1): 1 wave/SIMD -> up to 512 VGPR so layer1's
//    w[32] (128 VGPR) stays resident (was spilling at VGPR=100).
//  - Grid barrier: contention-free flag scan (per-block 128B slot, block 0
//    scans 256 slots with 256 threads, publishes gen). No contended RMW.
//  - Layer0 prefetches x[t+1] into registers pre-barrier (hides HBM latency
//    under the fence/barrier wait).
//  - h state stored bf16 (written by epilogue), c state lives in a register.
//  - mfma_f32_16x16x32_bf16: A[m=lane&15][k=quad*8+j], B(N,K)[n=lane&15][k=quad*8+j],
//    D[m=quad*4+reg][n=lane&15]  (guide-verified mapping, m90/m97 convention)
// ---------------------------------------------------------------------------

#define TT 1024
#define BB 64
#define CC 256
#define HH 512
#define Y_ELEMS (TT * BB * HH)
#define S_ELEMS (BB * HH)

typedef __attribute__((ext_vector_type(8))) short bf16x8;
typedef __attribute__((ext_vector_type(4))) float f32x4;
typedef unsigned int u32;
typedef unsigned short u16;

// ---- ws layout (bytes) ----
#define WS_BAR 0           // 256 slots * 128B (one per block)
#define WS_GEN 32768       // generation counter, own line
#define WS_BSUM0 36864     // 2048 f32
#define WS_BSUM1 45056     // 2048 f32
#define WS_H0 53248        // 2 * 32768 u16 (h0 ping-pong, bf16)
#define WS_H1 184320       // 2 * 32768 u16
#define WS_WPK0 315392     // 128*24*64*8 bf16  (layer0 packed W)
#define WS_WPK1 3461120    // 128*32*64*8 bf16  (layer1 packed W)
// end 7655424 (~7.66 MB)

__device__ __forceinline__ u16 f2b_rne(float f) {
    u32 u = __float_as_uint(f);
    return (u16)((u + 0x7FFFu + ((u >> 16) & 1u)) >> 16);
}
__device__ __forceinline__ u16 f2b_fast(float f) {  // round-half-up, 2 ops
    return (u16)((__float_as_uint(f) + 0x8000u) >> 16);
}
__device__ __forceinline__ float sigf(float z) { return 1.0f / (1.0f + __expf(-z)); }
__device__ __forceinline__ float tanh_f(float z) { return 2.0f / (1.0f + __expf(-2.0f * z)) - 1.0f; }

__device__ __forceinline__ bf16x8 pack8(float4 a, float4 b) {
    union { u16 u[8]; bf16x8 v; } r;
    r.u[0] = f2b_fast(a.x); r.u[1] = f2b_fast(a.y); r.u[2] = f2b_fast(a.z); r.u[3] = f2b_fast(a.w);
    r.u[4] = f2b_fast(b.x); r.u[5] = f2b_fast(b.y); r.u[6] = f2b_fast(b.z); r.u[7] = f2b_fast(b.w);
    return r.v;
}

// Contention-free grid barrier (monotone tick values, no resets, no RMW):
//   arrival: release-store target into this block's private 128B-spaced slot
//   block 0: 256 threads scan the 256 slots (1 load each), then publish gen
//   everyone: spin on gen, final acquire load invalidates stale caches.
// Data visibility: __syncthreads drains vmcnt; __threadfence + release store
// push h/out writes to the coherence point; readers' acquire-load invalidates.
__device__ __forceinline__ void grid_barrier(u32* slots, u32* gen, u32 target) {
    __syncthreads();
    if (threadIdx.x == 0) {
        __threadfence();
        __hip_atomic_store(&slots[(u32)blockIdx.x * 32], target, __ATOMIC_RELEASE, __HIP_MEMORY_SCOPE_AGENT);
    }
    if (blockIdx.x == 0) {
        while (__hip_atomic_load(&slots[(u32)threadIdx.x * 32], __ATOMIC_RELAXED, __HIP_MEMORY_SCOPE_AGENT) < target)
            __builtin_amdgcn_s_sleep(1);
        __syncthreads();
        if (threadIdx.x == 0)
            __hip_atomic_store(gen, target, __ATOMIC_RELEASE, __HIP_MEMORY_SCOPE_AGENT);
    }
    if (threadIdx.x == 0) {
        while (__hip_atomic_load(gen, __ATOMIC_RELAXED, __HIP_MEMORY_SCOPE_AGENT) < target)
            __builtin_amdgcn_s_sleep(1);
        (void)__hip_atomic_load(gen, __ATOMIC_ACQUIRE, __HIP_MEMORY_SCOPE_AGENT);
    }
    __syncthreads();
}

// ---- init: zero barrier region, bsum = bih+bhh, h buffers <- bf16(initial h) ----
__global__ void k_init(const float* __restrict__ bih0, const float* __restrict__ bhh0,
                       const float* __restrict__ bih1, const float* __restrict__ bhh1,
                       const float* __restrict__ h00, const float* __restrict__ h01,
                       unsigned char* __restrict__ ws) {
    u32* bar = (u32*)(ws + WS_BAR);
    float* bs0 = (float*)(ws + WS_BSUM0);
    float* bs1 = (float*)(ws + WS_BSUM1);
    u16* h0 = (u16*)(ws + WS_H0);
    u16* h1 = (u16*)(ws + WS_H1);
    int t = blockIdx.x * 256 + threadIdx.x;  // 32768 threads
    if (t < 9216) bar[t] = 0u;               // slots + gen (36864 B)
    if (t < 2048) { bs0[t] = bih0[t] + bhh0[t]; bs1[t] = bih1[t] + bhh1[t]; }
    if (t < S_ELEMS) { h0[t] = f2b_rne(h00[t]); h1[t] = f2b_rne(h01[t]); }
}

// ---- weight pack: fp32 [4H,K] -> bf16 B-frag order wpk[bidL][kt][lane][8] ----
// rows permuted: n-index (lane&15) = gg*4+jj  <->  W row = gg*512 + bidL*4 + jj
__global__ void k_wprep(const float* __restrict__ Wih0, const float* __restrict__ Whh0,
                        const float* __restrict__ Wih1, const float* __restrict__ Whh1,
                        unsigned char* __restrict__ ws) {
    u16* wpk0 = (u16*)(ws + WS_WPK0);
    u16* wpk1 = (u16*)(ws + WS_WPK1);
    int u = blockIdx.x * 256 + threadIdx.x;  // 458752 threads
    const float* s;
    u16* d;
    if (u < 128 * 24 * 64) {  // layer0: 8 x-tiles (K=256) + 16 h-tiles (K=512)
        int bidL = u / (24 * 64);
        int kt = (u >> 6) % 24;
        int lane = u & 63;
        int n = lane & 15, quad = lane >> 4;
        int row = (n >> 2) * 512 + bidL * 4 + (n & 3);
        int k = kt * 32 + quad * 8;
        s = (k < 256) ? (Wih0 + (size_t)row * 256 + k) : (Whh0 + (size_t)row * 512 + (k - 256));
        d = wpk0 + (size_t)((bidL * 24 + kt) * 64 + lane) * 8;
    } else {  // layer1: 16 y0-tiles + 16 h1-tiles (K=1024)
        int v = u - 128 * 24 * 64;
        int bidL = v / (32 * 64);
        int kt = (v >> 6) % 32;
        int lane = v & 63;
        int n = lane & 15, quad = lane >> 4;
        int row = (n >> 2) * 512 + bidL * 4 + (n & 3);
        int k = kt * 32 + quad * 8;
        s = (k < 512) ? (Wih1 + (size_t)row * 512 + k) : (Whh1 + (size_t)row * 512 + (k - 512));
        d = wpk1 + (size_t)((bidL * 32 + kt) * 64 + lane) * 8;
    }
    #pragma unroll
    for (int i = 0; i < 8; ++i) d[i] = f2b_rne(s[i]);
}

// ---- the persistent tick loop, templated on layer ----
template <int LAYER>
__device__ void run_ticks(const float* __restrict__ x, const float* __restrict__ c0,
                          float* __restrict__ out, unsigned char* __restrict__ ws, int bidL) {
    constexpr int NKT = (LAYER == 0) ? 24 : 32;
    u32* slots = (u32*)(ws + WS_BAR);
    u32* gen = (u32*)(ws + WS_GEN);
    const float* bs = (const float*)(ws + (LAYER == 0 ? WS_BSUM0 : WS_BSUM1));
    u16* h0b[2] = { (u16*)(ws + WS_H0), (u16*)(ws + WS_H0) + S_ELEMS };
    u16* h1b[2] = { (u16*)(ws + WS_H1), (u16*)(ws + WS_H1) + S_ELEMS };
    const u16* wpk = (const u16*)(ws + (LAYER == 0 ? WS_WPK0 : WS_WPK1));

    const int tid = threadIdx.x, lane = tid & 63, wave = tid >> 6;
    const int r16 = lane & 15, quad = lane >> 4, q8 = quad * 8;
    const int gg = r16 >> 2, jj = r16 & 3;
    const int b0 = wave * 16;
    const int col = bidL * 4 + jj;            // h column this lane finalizes
    const int myb = b0 + quad * 4 + gg;       // batch this lane finalizes
    const int sl0 = (quad << 4) | (0 << 2) | jj;
    const int sl1 = (quad << 4) | (1 << 2) | jj;
    const int sl2 = (quad << 4) | (2 << 2) | jj;
    const int sl3 = (quad << 4) | (3 << 2) | jj;

    // biases (hoisted), c state in register for the whole run
    const float bi = bs[0 * HH + col], bf_ = bs[1 * HH + col];
    const float bg = bs[2 * HH + col], bo = bs[3 * HH + col];
    float c = c0[myb * HH + col];

    // weight fragments: resident in VGPRs for all ticks (needs launch_bounds(256,1))
    bf16x8 w[NKT];
    {
        const u16* wp = wpk + (size_t)(bidL * NKT * 64 + lane) * 8;
        #pragma unroll
        for (int kt = 0; kt < NKT; ++kt) w[kt] = *(const bf16x8*)(wp + (size_t)kt * 64 * 8);
    }

    // layer0: x prefetch registers (t=0 issued before the loop)
    float4 xf0[8], xf1[8];
    if (LAYER == 0) {
        const float* xp = x + (size_t)(b0 + r16) * CC + q8;
        #pragma unroll
        for (int kt = 0; kt < 8; ++kt) {
            xf0[kt] = *(const float4*)(xp + kt * 32);
            xf1[kt] = *(const float4*)(xp + kt * 32 + 4);
        }
    }

    for (int i = 0; i <= TT; ++i) {
        const bool active = (LAYER == 0) ? (i < TT) : (i >= 1);
        const int t = (LAYER == 0) ? i : i - 1;
        if (active) {
            f32x4 aE = {0.f, 0.f, 0.f, 0.f}, aO = {0.f, 0.f, 0.f, 0.f};
            if (LAYER == 0) {
                // x projection from prefetched registers: fp32 -> bf16 in flight
                #pragma unroll
                for (int kt = 0; kt < 8; ++kt) {
                    bf16x8 a = pack8(xf0[kt], xf1[kt]);
                    if (kt & 1) aO = __builtin_amdgcn_mfma_f32_16x16x32_bf16(a, w[kt], aO, 0, 0, 0);
                    else        aE = __builtin_amdgcn_mfma_f32_16x16x32_bf16(a, w[kt], aE, 0, 0, 0);
                }
                // recurrent: h0 (bf16) at buf parity t&1
                const u16* hp = h0b[t & 1] + (size_t)(b0 + r16) * HH + q8;
                #pragma unroll
                for (int kt = 0; kt < 16; ++kt) {
                    bf16x8 a = *(const bf16x8*)(hp + kt * 32);
                    if (kt & 1) aO = __builtin_amdgcn_mfma_f32_16x16x32_bf16(a, w[8 + kt], aO, 0, 0, 0);
                    else        aE = __builtin_amdgcn_mfma_f32_16x16x32_bf16(a, w[8 + kt], aE, 0, 0, 0);
                }
                // prefetch x[t+1]: completes during epilogue/fence/barrier wait
                if (t + 1 < TT) {
                    const float* xp = x + ((size_t)(t + 1) * BB + b0 + r16) * CC + q8;
                    #pragma unroll
                    for (int kt = 0; kt < 8; ++kt) {
                        xf0[kt] = *(const float4*)(xp + kt * 32);
                        xf1[kt] = *(const float4*)(xp + kt * 32 + 4);
                    }
                }
            } else {
                // y0[t] = h0 written at tick t (parity (t+1)&1); h1 prev at t&1
                const u16* pa = h0b[(t + 1) & 1] + (size_t)(b0 + r16) * HH + q8;
                const u16* pb = h1b[t & 1] + (size_t)(b0 + r16) * HH + q8;
                #pragma unroll
                for (int kt = 0; kt < 16; ++kt) {
                    bf16x8 a = *(const bf16x8*)(pa + kt * 32);
                    if (kt & 1) aO = __builtin_amdgcn_mfma_f32_16x16x32_bf16(a, w[kt], aO, 0, 0, 0);
                    else        aE = __builtin_amdgcn_mfma_f32_16x16x32_bf16(a, w[kt], aE, 0, 0, 0);
                }
                #pragma unroll
                for (int kt = 0; kt < 16; ++kt) {
                    bf16x8 a = *(const bf16x8*)(pb + kt * 32);
                    if (kt & 1) aO = __builtin_amdgcn_mfma_f32_16x16x32_bf16(a, w[16 + kt], aO, 0, 0, 0);
                    else        aE = __builtin_amdgcn_mfma_f32_16x16x32_bf16(a, w[16 + kt], aE, 0, 0, 0);
                }
            }
            f32x4 acc = aE + aO;

            // gather the 4 gates for (myb, col): lanes sharing (quad,jj), gg = gate
            float gi = 0.f, gf = 0.f, gc = 0.f, go = 0.f;
            #pragma unroll
            for (int r = 0; r < 4; ++r) {
                float v0 = __shfl(acc[r], sl0, 64);
                float v1 = __shfl(acc[r], sl1, 64);
                float v2 = __shfl(acc[r], sl2, 64);
                float v3 = __shfl(acc[r], sl3, 64);
                if (r == gg) { gi = v0; gf = v1; gc = v2; go = v3; }
            }
            gi = sigf(gi + bi);
            gf = sigf(gf + bf_);
            gc = tanh_f(gc + bg);
            go = sigf(go + bo);
            c = gf * c + gi * gc;
            float h = go * tanh_f(c);

            u16* hw = (LAYER == 0) ? h0b[(t + 1) & 1] : h1b[(t + 1) & 1];
            hw[myb * HH + col] = f2b_rne(h);
            if (LAYER == 1) out[(size_t)t * S_ELEMS + myb * HH + col] = h;
            if (t == TT - 1) {
                float* fin = out + Y_ELEMS + (LAYER == 0 ? 0 : 2) * S_ELEMS;
                fin[myb * HH + col] = h;
                fin[S_ELEMS + myb * HH + col] = c;
            }
        }
        if (i < TT) grid_barrier(slots, gen, (u32)(i + 1));  // last tick: no consumer
    }
}

__global__ __launch_bounds__(256, 1) void k_lstm(const float* __restrict__ x,
                                                 const float* __restrict__ c00,
                                                 const float* __restrict__ c01,
                                                 float* __restrict__ out,
                                                 unsigned char* __restrict__ ws) {
    const int bid = blockIdx.x;
    if (bid < 128) run_ticks<0>(x, c00, out, ws, bid);
    else           run_ticks<1>(x, c01, out, ws, bid - 128);
}

extern "C" void kernel_launch(void* const* d_in, const int* in_sizes, int n_in,
                              void* d_out, int out_size, void* d_ws, size_t ws_size,
                              hipStream_t stream) {
    const float* x    = (const float*)d_in[0];
    const float* h0_0 = (const float*)d_in[1];
    const float* c0_0 = (const float*)d_in[2];
    const float* h0_1 = (const float*)d_in[3];
    const float* c0_1 = (const float*)d_in[4];
    const float* Wih0 = (const float*)d_in[5];
    const float* Whh0 = (const float*)d_in[6];
    const float* bih0 = (const float*)d_in[7];
    const float* bhh0 = (const float*)d_in[8];
    const float* Wih1 = (const float*)d_in[9];
    const float* Whh1 = (const float*)d_in[10];
    const float* bih1 = (const float*)d_in[11];
    const float* bhh1 = (const float*)d_in[12];
    float* out = (float*)d_out;
    unsigned char* ws = (unsigned char*)d_ws;

    k_init<<<128, 256, 0, stream>>>(bih0, bhh0, bih1, bhh1, h0_0, h0_1, ws);
    k_wprep<<<1792, 256, 0, stream>>>(Wih0, Whh0, Wih1, Whh1, ws);
    k_lstm<<<256, 256, 0, stream>>>(x, c0_0, c0_1, out, ws);
}

// Round 2
// 11166.536 us; speedup vs baseline: 1.9606x; 1.7282x over previous
//
#include <hip/hip_runtime.h>

// ---------------------------------------------------------------------------
// Persistent weight-stationary LSTM, bf16 MFMA, fence-free grid sync.
// T=1024 B=64 C=256 H=512, 2 layers, fp32 in/out.
//  - 256 blocks x 256 threads, 1 block/CU, co-resident; blocks 0..127 = layer0
//    (step t), 128..255 = layer1 (step t-1) -> one grid barrier per tick.
//  - NO acquire/release/threadfence in the tick loop: all cross-block data
//    (h state, barrier slots) moves via RELAXED agent-scope atomics (sc1 =
//    bypass L1/L2, coherent at LLC). Producer orders data-before-flag with
//    s_waitcnt vmcnt(0). This removes the per-tick buffer_wbl2/buffer_inv
//    L2 walks (32 per XCD per tick in R1) and keeps weights/x warm in L2.
//  - Barrier: single-hop. Block b stores monotone tick into slot[b]; every
//    block's 256 threads each scan one slot, then __syncthreads.
//  - Weights bf16, packed once into MFMA B-frag order (k_wprep), cached reads.
//  - h state bf16 ping-pong in ws (sc1 stores/loads); c state in a register.
//  - mfma_f32_16x16x32_bf16: A[m=lane&15][k=quad*8+j], B(N,K)[n=lane&15][k=quad*8+j],
//    D[m=quad*4+reg][n=lane&15]  (guide-verified mapping, m90/m97 convention)
// ---------------------------------------------------------------------------

#define TT 1024
#define BB 64
#define CC 256
#define HH 512
#define Y_ELEMS (TT * BB * HH)
#define S_ELEMS (BB * HH)

typedef __attribute__((ext_vector_type(8))) short bf16x8;
typedef __attribute__((ext_vector_type(4))) float f32x4;
typedef unsigned int u32;
typedef unsigned short u16;
typedef unsigned long long u64;

// ---- ws layout (bytes) ----
#define WS_BAR 0           // 256 slots * 128B (one per block)
#define WS_GEN 32768       // (unused, kept for layout stability)
#define WS_BSUM0 36864     // 2048 f32
#define WS_BSUM1 45056     // 2048 f32
#define WS_H0 53248        // 2 * 32768 u16 (h0 ping-pong, bf16)
#define WS_H1 184320       // 2 * 32768 u16
#define WS_WPK0 315392     // 128*24*64*8 bf16  (layer0 packed W)
#define WS_WPK1 3461120    // 128*32*64*8 bf16  (layer1 packed W)
// end 7655424 (~7.66 MB)

__device__ __forceinline__ u16 f2b_rne(float f) {
    u32 u = __float_as_uint(f);
    return (u16)((u + 0x7FFFu + ((u >> 16) & 1u)) >> 16);
}
__device__ __forceinline__ u16 f2b_fast(float f) {  // round-half-up, 2 ops
    return (u16)((__float_as_uint(f) + 0x8000u) >> 16);
}
__device__ __forceinline__ float sigf(float z) { return 1.0f / (1.0f + __expf(-z)); }
__device__ __forceinline__ float tanh_f(float z) { return 2.0f / (1.0f + __expf(-2.0f * z)) - 1.0f; }

__device__ __forceinline__ bf16x8 pack8(float4 a, float4 b) {
    union { u16 u[8]; bf16x8 v; } r;
    r.u[0] = f2b_fast(a.x); r.u[1] = f2b_fast(a.y); r.u[2] = f2b_fast(a.z); r.u[3] = f2b_fast(a.w);
    r.u[4] = f2b_fast(b.x); r.u[5] = f2b_fast(b.y); r.u[6] = f2b_fast(b.z); r.u[7] = f2b_fast(b.w);
    return r.v;
}

// 16B h-fragment load that bypasses L1/L2 (relaxed agent atomics -> sc1).
// No fence, no buffer_inv: data is coherent at LLC because producers store sc1.
__device__ __forceinline__ bf16x8 ld_frag_sc(const u16* p) {
    union { u64 q[2]; bf16x8 v; } r;
    r.q[0] = __hip_atomic_load((u64*)p,     __ATOMIC_RELAXED, __HIP_MEMORY_SCOPE_AGENT);
    r.q[1] = __hip_atomic_load((u64*)p + 1, __ATOMIC_RELAXED, __HIP_MEMORY_SCOPE_AGENT);
    return r.v;
}
__device__ __forceinline__ void st_h_sc(u16* p, u16 v) {
    __hip_atomic_store(p, v, __ATOMIC_RELAXED, __HIP_MEMORY_SCOPE_AGENT);
}

// Fence-free single-hop grid barrier with monotone tick values.
// Caller guarantees each thread's sc1 data stores are drained (vmcnt(0))
// before entry. slot store is sc1; readers scan sc1 -> no staleness possible.
__device__ __forceinline__ void grid_barrier(u32* slots, u32 target) {
    __syncthreads();
    if (threadIdx.x == 0)
        __hip_atomic_store(&slots[(u32)blockIdx.x * 32], target, __ATOMIC_RELAXED, __HIP_MEMORY_SCOPE_AGENT);
    // thread tid watches block tid's slot (256 threads <-> 256 blocks)
    while (__hip_atomic_load(&slots[(u32)threadIdx.x * 32], __ATOMIC_RELAXED, __HIP_MEMORY_SCOPE_AGENT) < target)
        __builtin_amdgcn_s_sleep(2);
    __syncthreads();
}

// ---- init: zero barrier region, bsum = bih+bhh, h buffers <- bf16(initial h) ----
__global__ void k_init(const float* __restrict__ bih0, const float* __restrict__ bhh0,
                       const float* __restrict__ bih1, const float* __restrict__ bhh1,
                       const float* __restrict__ h00, const float* __restrict__ h01,
                       unsigned char* __restrict__ ws) {
    u32* bar = (u32*)(ws + WS_BAR);
    float* bs0 = (float*)(ws + WS_BSUM0);
    float* bs1 = (float*)(ws + WS_BSUM1);
    u16* h0 = (u16*)(ws + WS_H0);
    u16* h1 = (u16*)(ws + WS_H1);
    int t = blockIdx.x * 256 + threadIdx.x;  // 32768 threads
    if (t < 9216) bar[t] = 0u;               // slots (+legacy gen) region
    if (t < 2048) { bs0[t] = bih0[t] + bhh0[t]; bs1[t] = bih1[t] + bhh1[t]; }
    if (t < S_ELEMS) { h0[t] = f2b_rne(h00[t]); h1[t] = f2b_rne(h01[t]); }
}

// ---- weight pack: fp32 [4H,K] -> bf16 B-frag order wpk[bidL][kt][lane][8] ----
// rows permuted: n-index (lane&15) = gg*4+jj  <->  W row = gg*512 + bidL*4 + jj
__global__ void k_wprep(const float* __restrict__ Wih0, const float* __restrict__ Whh0,
                        const float* __restrict__ Wih1, const float* __restrict__ Whh1,
                        unsigned char* __restrict__ ws) {
    u16* wpk0 = (u16*)(ws + WS_WPK0);
    u16* wpk1 = (u16*)(ws + WS_WPK1);
    int u = blockIdx.x * 256 + threadIdx.x;  // 458752 threads
    const float* s;
    u16* d;
    if (u < 128 * 24 * 64) {  // layer0: 8 x-tiles (K=256) + 16 h-tiles (K=512)
        int bidL = u / (24 * 64);
        int kt = (u >> 6) % 24;
        int lane = u & 63;
        int n = lane & 15, quad = lane >> 4;
        int row = (n >> 2) * 512 + bidL * 4 + (n & 3);
        int k = kt * 32 + quad * 8;
        s = (k < 256) ? (Wih0 + (size_t)row * 256 + k) : (Whh0 + (size_t)row * 512 + (k - 256));
        d = wpk0 + (size_t)((bidL * 24 + kt) * 64 + lane) * 8;
    } else {  // layer1: 16 y0-tiles + 16 h1-tiles (K=1024)
        int v = u - 128 * 24 * 64;
        int bidL = v / (32 * 64);
        int kt = (v >> 6) % 32;
        int lane = v & 63;
        int n = lane & 15, quad = lane >> 4;
        int row = (n >> 2) * 512 + bidL * 4 + (n & 3);
        int k = kt * 32 + quad * 8;
        s = (k < 512) ? (Wih1 + (size_t)row * 512 + k) : (Whh1 + (size_t)row * 512 + (k - 512));
        d = wpk1 + (size_t)((bidL * 32 + kt) * 64 + lane) * 8;
    }
    #pragma unroll
    for (int i = 0; i < 8; ++i) d[i] = f2b_rne(s[i]);
}

// ---- the persistent tick loop, templated on layer ----
template <int LAYER>
__device__ void run_ticks(const float* __restrict__ x, const float* __restrict__ c0,
                          float* __restrict__ out, unsigned char* __restrict__ ws, int bidL) {
    constexpr int NKT = (LAYER == 0) ? 24 : 32;
    u32* slots = (u32*)(ws + WS_BAR);
    const float* bs = (const float*)(ws + (LAYER == 0 ? WS_BSUM0 : WS_BSUM1));
    u16* h0b[2] = { (u16*)(ws + WS_H0), (u16*)(ws + WS_H0) + S_ELEMS };
    u16* h1b[2] = { (u16*)(ws + WS_H1), (u16*)(ws + WS_H1) + S_ELEMS };
    const u16* wpk = (const u16*)(ws + (LAYER == 0 ? WS_WPK0 : WS_WPK1));

    const int tid = threadIdx.x, lane = tid & 63, wave = tid >> 6;
    const int r16 = lane & 15, quad = lane >> 4, q8 = quad * 8;
    const int gg = r16 >> 2, jj = r16 & 3;
    const int b0 = wave * 16;
    const int col = bidL * 4 + jj;            // h column this lane finalizes
    const int myb = b0 + quad * 4 + gg;       // batch this lane finalizes
    const int sl0 = (quad << 4) | (0 << 2) | jj;
    const int sl1 = (quad << 4) | (1 << 2) | jj;
    const int sl2 = (quad << 4) | (2 << 2) | jj;
    const int sl3 = (quad << 4) | (3 << 2) | jj;

    // biases (hoisted), c state in register for the whole run
    const float bi = bs[0 * HH + col], bf_ = bs[1 * HH + col];
    const float bg = bs[2 * HH + col], bo = bs[3 * HH + col];
    float c = c0[myb * HH + col];

    // weight fragments: cached loads; with no per-tick L2 invalidate these stay
    // warm in L1/L2 even if the compiler rematerializes them in the loop.
    bf16x8 w[NKT];
    {
        const u16* wp = wpk + (size_t)(bidL * NKT * 64 + lane) * 8;
        #pragma unroll
        for (int kt = 0; kt < NKT; ++kt) w[kt] = *(const bf16x8*)(wp + (size_t)kt * 64 * 8);
    }

    // layer0: x prefetch registers (t=0 issued before the loop)
    float4 xf0[8], xf1[8];
    if (LAYER == 0) {
        const float* xp = x + (size_t)(b0 + r16) * CC + q8;
        #pragma unroll
        for (int kt = 0; kt < 8; ++kt) {
            xf0[kt] = *(const float4*)(xp + kt * 32);
            xf1[kt] = *(const float4*)(xp + kt * 32 + 4);
        }
    }

    for (int i = 0; i <= TT; ++i) {
        const bool active = (LAYER == 0) ? (i < TT) : (i >= 1);
        const int t = (LAYER == 0) ? i : i - 1;
        if (active) {
            f32x4 aE = {0.f, 0.f, 0.f, 0.f}, aO = {0.f, 0.f, 0.f, 0.f};
            if (LAYER == 0) {
                // batch-issue the 16 recurrent h fragments (sc1, one LLC round)
                bf16x8 afr[16];
                const u16* hp = h0b[t & 1] + (size_t)(b0 + r16) * HH + q8;
                #pragma unroll
                for (int kt = 0; kt < 16; ++kt) afr[kt] = ld_frag_sc(hp + kt * 32);
                // x projection from prefetched registers overlaps the h-load latency
                #pragma unroll
                for (int kt = 0; kt < 8; ++kt) {
                    bf16x8 a = pack8(xf0[kt], xf1[kt]);
                    if (kt & 1) aO = __builtin_amdgcn_mfma_f32_16x16x32_bf16(a, w[kt], aO, 0, 0, 0);
                    else        aE = __builtin_amdgcn_mfma_f32_16x16x32_bf16(a, w[kt], aE, 0, 0, 0);
                }
                #pragma unroll
                for (int kt = 0; kt < 16; ++kt) {
                    if (kt & 1) aO = __builtin_amdgcn_mfma_f32_16x16x32_bf16(afr[kt], w[8 + kt], aO, 0, 0, 0);
                    else        aE = __builtin_amdgcn_mfma_f32_16x16x32_bf16(afr[kt], w[8 + kt], aE, 0, 0, 0);
                }
                // prefetch x[t+1] (cached): completes during epilogue/barrier wait
                if (t + 1 < TT) {
                    const float* xp = x + ((size_t)(t + 1) * BB + b0 + r16) * CC + q8;
                    #pragma unroll
                    for (int kt = 0; kt < 8; ++kt) {
                        xf0[kt] = *(const float4*)(xp + kt * 32);
                        xf1[kt] = *(const float4*)(xp + kt * 32 + 4);
                    }
                }
            } else {
                // y0[t] = h0 written at tick t (parity (t+1)&1); h1 prev at t&1
                bf16x8 afr[32];
                const u16* pa = h0b[(t + 1) & 1] + (size_t)(b0 + r16) * HH + q8;
                const u16* pb = h1b[t & 1] + (size_t)(b0 + r16) * HH + q8;
                #pragma unroll
                for (int kt = 0; kt < 16; ++kt) afr[kt] = ld_frag_sc(pa + kt * 32);
                #pragma unroll
                for (int kt = 0; kt < 16; ++kt) afr[16 + kt] = ld_frag_sc(pb + kt * 32);
                #pragma unroll
                for (int kt = 0; kt < 32; ++kt) {
                    if (kt & 1) aO = __builtin_amdgcn_mfma_f32_16x16x32_bf16(afr[kt], w[kt], aO, 0, 0, 0);
                    else        aE = __builtin_amdgcn_mfma_f32_16x16x32_bf16(afr[kt], w[kt], aE, 0, 0, 0);
                }
            }
            f32x4 acc = aE + aO;

            // gather the 4 gates for (myb, col): lanes sharing (quad,jj), gg = gate
            float gi = 0.f, gf = 0.f, gc = 0.f, go = 0.f;
            #pragma unroll
            for (int r = 0; r < 4; ++r) {
                float v0 = __shfl(acc[r], sl0, 64);
                float v1 = __shfl(acc[r], sl1, 64);
                float v2 = __shfl(acc[r], sl2, 64);
                float v3 = __shfl(acc[r], sl3, 64);
                if (r == gg) { gi = v0; gf = v1; gc = v2; go = v3; }
            }
            gi = sigf(gi + bi);
            gf = sigf(gf + bf_);
            gc = tanh_f(gc + bg);
            go = sigf(go + bo);
            c = gf * c + gi * gc;
            float h = go * tanh_f(c);

            u16* hw = (LAYER == 0) ? h0b[(t + 1) & 1] : h1b[(t + 1) & 1];
            st_h_sc(&hw[myb * HH + col], f2b_rne(h));       // sc1 write-through
            if (LAYER == 1) out[(size_t)t * S_ELEMS + myb * HH + col] = h;  // host-only
            if (t == TT - 1) {
                float* fin = out + Y_ELEMS + (LAYER == 0 ? 0 : 2) * S_ELEMS;
                fin[myb * HH + col] = h;
                fin[S_ELEMS + myb * HH + col] = c;
            }
            // drain this thread's sc1 h-store (and everything else) to LLC
            // before the barrier flag can be raised.
            asm volatile("s_waitcnt vmcnt(0)" ::: "memory");
        }
        if (i < TT) grid_barrier(slots, (u32)(i + 1));  // last tick: no consumer
    }
}

__global__ __launch_bounds__(256, 1) void k_lstm(const float* __restrict__ x,
                                                 const float* __restrict__ c00,
                                                 const float* __restrict__ c01,
                                                 float* __restrict__ out,
                                                 unsigned char* __restrict__ ws) {
    const int bid = blockIdx.x;
    if (bid < 128) run_ticks<0>(x, c00, out, ws, bid);
    else           run_ticks<1>(x, c01, out, ws, bid - 128);
}

extern "C" void kernel_launch(void* const* d_in, const int* in_sizes, int n_in,
                              void* d_out, int out_size, void* d_ws, size_t ws_size,
                              hipStream_t stream) {
    const float* x    = (const float*)d_in[0];
    const float* h0_0 = (const float*)d_in[1];
    const float* c0_0 = (const float*)d_in[2];
    const float* h0_1 = (const float*)d_in[3];
    const float* c0_1 = (const float*)d_in[4];
    const float* Wih0 = (const float*)d_in[5];
    const float* Whh0 = (const float*)d_in[6];
    const float* bih0 = (const float*)d_in[7];
    const float* bhh0 = (const float*)d_in[8];
    const float* Wih1 = (const float*)d_in[9];
    const float* Whh1 = (const float*)d_in[10];
    const float* bih1 = (const float*)d_in[11];
    const float* bhh1 = (const float*)d_in[12];
    float* out = (float*)d_out;
    unsigned char* ws = (unsigned char*)d_ws;

    k_init<<<128, 256, 0, stream>>>(bih0, bhh0, bih1, bhh1, h0_0, h0_1, ws);
    k_wprep<<<1792, 256, 0, stream>>>(Wih0, Whh0, Wih1, Whh1, ws);
    k_lstm<<<256, 256, 0, stream>>>(x, c0_0, c0_1, out, ws);
}

// Round 3
// 10127.866 us; speedup vs baseline: 2.1617x; 1.1026x over previous
//
#include <hip/hip_runtime.h>

// ---------------------------------------------------------------------------
// Persistent weight-stationary LSTM, bf16 MFMA, fence-free grid sync.
// T=1024 B=64 C=256 H=512, 2 layers, fp32 in/out.
//  - 256 blocks x 256 threads, 1 block/CU; blocks 0..127 = layer0 (step t),
//    128..255 = layer1 (step t-1) -> one grid barrier per tick.
//  - No acquire/release/threadfence in the tick loop: cross-block data (h,
//    barrier slots) via RELAXED agent-scope atomics (sc1, LLC-coherent).
//    Producer orders data-before-flag with s_waitcnt vmcnt(0) + syncthreads.
//  - Weights loaded once into VGPRs and PINNED via asm identity (cannot be
//    rematerialized) -> all 32 h-fragment loads can be in flight in ONE LLC
//    round (was 3-5 register-starved serialized rounds at VGPR=104).
//  - Critical path per tick: h-store -> vmcnt(0) -> syncthreads -> flag.
//    out stores / final stores / x[t+1] prefetch issue AFTER the flag, in the
//    barrier-wait shadow.
//  - Barrier: block b flag-stores monotone tick in slot[b]; wave 0 polls 4
//    slots/thread (4 loads in flight, min-reduce), no s_sleep; other waves
//    wait at the closing __syncthreads.
//  - mfma_f32_16x16x32_bf16: A[m=lane&15][k=quad*8+j], B(N,K)[n=lane&15][k=quad*8+j],
//    D[m=quad*4+reg][n=lane&15]  (guide-verified mapping, m90/m97 convention)
// ---------------------------------------------------------------------------

#define TT 1024
#define BB 64
#define CC 256
#define HH 512
#define Y_ELEMS (TT * BB * HH)
#define S_ELEMS (BB * HH)

typedef __attribute__((ext_vector_type(8))) short bf16x8;
typedef __attribute__((ext_vector_type(4))) float f32x4;
typedef unsigned int u32;
typedef unsigned short u16;
typedef unsigned long long u64;

// ---- ws layout (bytes) ----
#define WS_BAR 0           // 256 slots * 128B (one per block)
#define WS_GEN 32768       // (unused, kept for layout stability)
#define WS_BSUM0 36864     // 2048 f32
#define WS_BSUM1 45056     // 2048 f32
#define WS_H0 53248        // 2 * 32768 u16 (h0 ping-pong, bf16)
#define WS_H1 184320       // 2 * 32768 u16
#define WS_WPK0 315392     // 128*24*64*8 bf16  (layer0 packed W)
#define WS_WPK1 3461120    // 128*32*64*8 bf16  (layer1 packed W)
// end 7655424 (~7.66 MB)

__device__ __forceinline__ u16 f2b_rne(float f) {
    u32 u = __float_as_uint(f);
    return (u16)((u + 0x7FFFu + ((u >> 16) & 1u)) >> 16);
}
__device__ __forceinline__ u16 f2b_fast(float f) {  // round-half-up, 2 ops
    return (u16)((__float_as_uint(f) + 0x8000u) >> 16);
}
__device__ __forceinline__ float sigf(float z) { return 1.0f / (1.0f + __expf(-z)); }
__device__ __forceinline__ float tanh_f(float z) { return 2.0f / (1.0f + __expf(-2.0f * z)) - 1.0f; }

__device__ __forceinline__ bf16x8 pack8(float4 a, float4 b) {
    union { u16 u[8]; bf16x8 v; } r;
    r.u[0] = f2b_fast(a.x); r.u[1] = f2b_fast(a.y); r.u[2] = f2b_fast(a.z); r.u[3] = f2b_fast(a.w);
    r.u[4] = f2b_fast(b.x); r.u[5] = f2b_fast(b.y); r.u[6] = f2b_fast(b.z); r.u[7] = f2b_fast(b.w);
    return r.v;
}

// 16B h-fragment load that stays LLC-coherent (relaxed agent atomics -> sc1).
__device__ __forceinline__ bf16x8 ld_frag_sc(const u16* p) {
    union { u64 q[2]; bf16x8 v; } r;
    r.q[0] = __hip_atomic_load((u64*)p,     __ATOMIC_RELAXED, __HIP_MEMORY_SCOPE_AGENT);
    r.q[1] = __hip_atomic_load((u64*)p + 1, __ATOMIC_RELAXED, __HIP_MEMORY_SCOPE_AGENT);
    return r.v;
}
__device__ __forceinline__ void st_h_sc(u16* p, u16 v) {
    __hip_atomic_store(p, v, __ATOMIC_RELAXED, __HIP_MEMORY_SCOPE_AGENT);
}

// ---- init: zero barrier region, bsum = bih+bhh, h buffers <- bf16(initial h) ----
__global__ void k_init(const float* __restrict__ bih0, const float* __restrict__ bhh0,
                       const float* __restrict__ bih1, const float* __restrict__ bhh1,
                       const float* __restrict__ h00, const float* __restrict__ h01,
                       unsigned char* __restrict__ ws) {
    u32* bar = (u32*)(ws + WS_BAR);
    float* bs0 = (float*)(ws + WS_BSUM0);
    float* bs1 = (float*)(ws + WS_BSUM1);
    u16* h0 = (u16*)(ws + WS_H0);
    u16* h1 = (u16*)(ws + WS_H1);
    int t = blockIdx.x * 256 + threadIdx.x;  // 32768 threads
    if (t < 9216) bar[t] = 0u;               // slots (+legacy gen) region
    if (t < 2048) { bs0[t] = bih0[t] + bhh0[t]; bs1[t] = bih1[t] + bhh1[t]; }
    if (t < S_ELEMS) { h0[t] = f2b_rne(h00[t]); h1[t] = f2b_rne(h01[t]); }
}

// ---- weight pack: fp32 [4H,K] -> bf16 B-frag order wpk[bidL][kt][lane][8] ----
// rows permuted: n-index (lane&15) = gg*4+jj  <->  W row = gg*512 + bidL*4 + jj
__global__ void k_wprep(const float* __restrict__ Wih0, const float* __restrict__ Whh0,
                        const float* __restrict__ Wih1, const float* __restrict__ Whh1,
                        unsigned char* __restrict__ ws) {
    u16* wpk0 = (u16*)(ws + WS_WPK0);
    u16* wpk1 = (u16*)(ws + WS_WPK1);
    int u = blockIdx.x * 256 + threadIdx.x;  // 458752 threads
    const float* s;
    u16* d;
    if (u < 128 * 24 * 64) {  // layer0: 8 x-tiles (K=256) + 16 h-tiles (K=512)
        int bidL = u / (24 * 64);
        int kt = (u >> 6) % 24;
        int lane = u & 63;
        int n = lane & 15, quad = lane >> 4;
        int row = (n >> 2) * 512 + bidL * 4 + (n & 3);
        int k = kt * 32 + quad * 8;
        s = (k < 256) ? (Wih0 + (size_t)row * 256 + k) : (Whh0 + (size_t)row * 512 + (k - 256));
        d = wpk0 + (size_t)((bidL * 24 + kt) * 64 + lane) * 8;
    } else {  // layer1: 16 y0-tiles + 16 h1-tiles (K=1024)
        int v = u - 128 * 24 * 64;
        int bidL = v / (32 * 64);
        int kt = (v >> 6) % 32;
        int lane = v & 63;
        int n = lane & 15, quad = lane >> 4;
        int row = (n >> 2) * 512 + bidL * 4 + (n & 3);
        int k = kt * 32 + quad * 8;
        s = (k < 512) ? (Wih1 + (size_t)row * 512 + k) : (Whh1 + (size_t)row * 512 + (k - 512));
        d = wpk1 + (size_t)((bidL * 32 + kt) * 64 + lane) * 8;
    }
    #pragma unroll
    for (int i = 0; i < 8; ++i) d[i] = f2b_rne(s[i]);
}

// ---- the persistent tick loop, templated on layer ----
template <int LAYER>
__device__ void run_ticks(const float* __restrict__ x, const float* __restrict__ c0,
                          float* __restrict__ out, unsigned char* __restrict__ ws, int bidL) {
    constexpr int NKT = (LAYER == 0) ? 24 : 32;
    u32* slots = (u32*)(ws + WS_BAR);
    const float* bs = (const float*)(ws + (LAYER == 0 ? WS_BSUM0 : WS_BSUM1));
    u16* h0b[2] = { (u16*)(ws + WS_H0), (u16*)(ws + WS_H0) + S_ELEMS };
    u16* h1b[2] = { (u16*)(ws + WS_H1), (u16*)(ws + WS_H1) + S_ELEMS };
    const u16* wpk = (const u16*)(ws + (LAYER == 0 ? WS_WPK0 : WS_WPK1));

    const int tid = threadIdx.x, lane = tid & 63, wave = tid >> 6;
    const int r16 = lane & 15, quad = lane >> 4, q8 = quad * 8;
    const int gg = r16 >> 2, jj = r16 & 3;
    const int b0 = wave * 16;
    const int col = bidL * 4 + jj;            // h column this lane finalizes
    const int myb = b0 + quad * 4 + gg;       // batch this lane finalizes
    const int sl0 = (quad << 4) | (0 << 2) | jj;
    const int sl1 = (quad << 4) | (1 << 2) | jj;
    const int sl2 = (quad << 4) | (2 << 2) | jj;
    const int sl3 = (quad << 4) | (3 << 2) | jj;

    // biases (hoisted), c state in register for the whole run
    const float bi = bs[0 * HH + col], bf_ = bs[1 * HH + col];
    const float bg = bs[2 * HH + col], bo = bs[3 * HH + col];
    float c = c0[myb * HH + col];

    // weight fragments: load once, then PIN in VGPRs via asm identity.
    // The asm is volatile & non-re-executable -> compiler cannot rematerialize
    // the loads inside the tick loop; values stay live in registers all run.
    f32x4 wf[NKT];
    {
        const u16* wp = wpk + (size_t)(bidL * NKT * 64 + lane) * 8;
        #pragma unroll
        for (int kt = 0; kt < NKT; ++kt) wf[kt] = *(const f32x4*)(wp + (size_t)kt * 64 * 8);
        #pragma unroll
        for (int kt = 0; kt < NKT; ++kt) asm volatile("" : "+v"(wf[kt]));
    }

    // layer0: x prefetch registers (t=0 issued before the loop)
    float4 xf0[8], xf1[8];
    if (LAYER == 0) {
        const float* xp = x + (size_t)(b0 + r16) * CC + q8;
        #pragma unroll
        for (int kt = 0; kt < 8; ++kt) {
            xf0[kt] = *(const float4*)(xp + kt * 32);
            xf1[kt] = *(const float4*)(xp + kt * 32 + 4);
        }
    }

    for (int i = 0; i <= TT; ++i) {
        const bool active = (LAYER == 0) ? (i < TT) : (i >= 1);
        const int t = (LAYER == 0) ? i : i - 1;
        float h = 0.f;
        if (active) {
            f32x4 aE = {0.f, 0.f, 0.f, 0.f}, aO = {0.f, 0.f, 0.f, 0.f};
            if (LAYER == 0) {
                // batch-issue the 16 recurrent h fragments (sc1, one LLC round)
                bf16x8 afr[16];
                const u16* hp = h0b[t & 1] + (size_t)(b0 + r16) * HH + q8;
                #pragma unroll
                for (int kt = 0; kt < 16; ++kt) afr[kt] = ld_frag_sc(hp + kt * 32);
                // x projection from prefetched registers overlaps the h-load latency
                #pragma unroll
                for (int kt = 0; kt < 8; ++kt) {
                    bf16x8 a = pack8(xf0[kt], xf1[kt]);
                    bf16x8 wv = __builtin_bit_cast(bf16x8, wf[kt]);
                    if (kt & 1) aO = __builtin_amdgcn_mfma_f32_16x16x32_bf16(a, wv, aO, 0, 0, 0);
                    else        aE = __builtin_amdgcn_mfma_f32_16x16x32_bf16(a, wv, aE, 0, 0, 0);
                }
                #pragma unroll
                for (int kt = 0; kt < 16; ++kt) {
                    bf16x8 wv = __builtin_bit_cast(bf16x8, wf[8 + kt]);
                    if (kt & 1) aO = __builtin_amdgcn_mfma_f32_16x16x32_bf16(afr[kt], wv, aO, 0, 0, 0);
                    else        aE = __builtin_amdgcn_mfma_f32_16x16x32_bf16(afr[kt], wv, aE, 0, 0, 0);
                }
            } else {
                // y0[t] = h0 written at tick t (parity (t+1)&1); h1 prev at t&1
                bf16x8 afr[32];
                const u16* pa = h0b[(t + 1) & 1] + (size_t)(b0 + r16) * HH + q8;
                const u16* pb = h1b[t & 1] + (size_t)(b0 + r16) * HH + q8;
                #pragma unroll
                for (int kt = 0; kt < 16; ++kt) afr[kt] = ld_frag_sc(pa + kt * 32);
                #pragma unroll
                for (int kt = 0; kt < 16; ++kt) afr[16 + kt] = ld_frag_sc(pb + kt * 32);
                #pragma unroll
                for (int kt = 0; kt < 32; ++kt) {
                    bf16x8 wv = __builtin_bit_cast(bf16x8, wf[kt]);
                    if (kt & 1) aO = __builtin_amdgcn_mfma_f32_16x16x32_bf16(afr[kt], wv, aO, 0, 0, 0);
                    else        aE = __builtin_amdgcn_mfma_f32_16x16x32_bf16(afr[kt], wv, aE, 0, 0, 0);
                }
            }
            f32x4 acc = aE + aO;

            // gather the 4 gates for (myb, col): lanes sharing (quad,jj), gg = gate
            float gi = 0.f, gf = 0.f, gc = 0.f, go = 0.f;
            #pragma unroll
            for (int r = 0; r < 4; ++r) {
                float v0 = __shfl(acc[r], sl0, 64);
                float v1 = __shfl(acc[r], sl1, 64);
                float v2 = __shfl(acc[r], sl2, 64);
                float v3 = __shfl(acc[r], sl3, 64);
                if (r == gg) { gi = v0; gf = v1; gc = v2; go = v3; }
            }
            gi = sigf(gi + bi);
            gf = sigf(gf + bf_);
            gc = tanh_f(gc + bg);
            go = sigf(go + bo);
            c = gf * c + gi * gc;
            h = go * tanh_f(c);

            u16* hw = (LAYER == 0) ? h0b[(t + 1) & 1] : h1b[(t + 1) & 1];
            st_h_sc(&hw[myb * HH + col], f2b_rne(h));       // the only pre-flag store
        }
        // ---- barrier arrival: drain h store only, then raise flag ----
        if (i < TT) {
            asm volatile("s_waitcnt vmcnt(0)" ::: "memory");
            __syncthreads();   // all waves of this block drained
            if (tid == 0)
                __hip_atomic_store(&slots[(u32)blockIdx.x * 32], (u32)(i + 1),
                                   __ATOMIC_RELAXED, __HIP_MEMORY_SCOPE_AGENT);
        }
        // ---- shadow work while the flag propagates / peers finish ----
        if (active) {
            if (LAYER == 1) out[(size_t)t * S_ELEMS + myb * HH + col] = h;
            if (t == TT - 1) {
                float* fin = out + Y_ELEMS + (LAYER == 0 ? 0 : 2) * S_ELEMS;
                fin[myb * HH + col] = h;
                fin[S_ELEMS + myb * HH + col] = c;
            }
        }
        if (LAYER == 0 && i + 1 < TT) {      // prefetch x[t+1] into registers
            const float* xp = x + ((size_t)(i + 1) * BB + b0 + r16) * CC + q8;
            #pragma unroll
            for (int kt = 0; kt < 8; ++kt) {
                xf0[kt] = *(const float4*)(xp + kt * 32);
                xf1[kt] = *(const float4*)(xp + kt * 32 + 4);
            }
        }
        // ---- barrier completion: wave 0 polls 4 slots/thread, no sleep ----
        if (i < TT) {
            if (tid < 64) {
                const u32 tgt = (u32)(i + 1);
                const u32* p0 = slots + ((u32)tid * 4 + 0) * 32;
                const u32* p1 = slots + ((u32)tid * 4 + 1) * 32;
                const u32* p2 = slots + ((u32)tid * 4 + 2) * 32;
                const u32* p3 = slots + ((u32)tid * 4 + 3) * 32;
                u32 m;
                do {
                    u32 a = __hip_atomic_load(p0, __ATOMIC_RELAXED, __HIP_MEMORY_SCOPE_AGENT);
                    u32 b = __hip_atomic_load(p1, __ATOMIC_RELAXED, __HIP_MEMORY_SCOPE_AGENT);
                    u32 e = __hip_atomic_load(p2, __ATOMIC_RELAXED, __HIP_MEMORY_SCOPE_AGENT);
                    u32 d = __hip_atomic_load(p3, __ATOMIC_RELAXED, __HIP_MEMORY_SCOPE_AGENT);
                    m = min(min(a, b), min(e, d));
                } while (m < tgt);
            }
            __syncthreads();
        }
    }
}

__global__ __launch_bounds__(256, 1) void k_lstm(const float* __restrict__ x,
                                                 const float* __restrict__ c00,
                                                 const float* __restrict__ c01,
                                                 float* __restrict__ out,
                                                 unsigned char* __restrict__ ws) {
    const int bid = blockIdx.x;
    if (bid < 128) run_ticks<0>(x, c00, out, ws, bid);
    else           run_ticks<1>(x, c01, out, ws, bid - 128);
}

extern "C" void kernel_launch(void* const* d_in, const int* in_sizes, int n_in,
                              void* d_out, int out_size, void* d_ws, size_t ws_size,
                              hipStream_t stream) {
    const float* x    = (const float*)d_in[0];
    const float* h0_0 = (const float*)d_in[1];
    const float* c0_0 = (const float*)d_in[2];
    const float* h0_1 = (const float*)d_in[3];
    const float* c0_1 = (const float*)d_in[4];
    const float* Wih0 = (const float*)d_in[5];
    const float* Whh0 = (const float*)d_in[6];
    const float* bih0 = (const float*)d_in[7];
    const float* bhh0 = (const float*)d_in[8];
    const float* Wih1 = (const float*)d_in[9];
    const float* Whh1 = (const float*)d_in[10];
    const float* bih1 = (const float*)d_in[11];
    const float* bhh1 = (const float*)d_in[12];
    float* out = (float*)d_out;
    unsigned char* ws = (unsigned char*)d_ws;

    k_init<<<128, 256, 0, stream>>>(bih0, bhh0, bih1, bhh1, h0_0, h0_1, ws);
    k_wprep<<<1792, 256, 0, stream>>>(Wih0, Whh0, Wih1, Whh1, ws);
    k_lstm<<<256, 256, 0, stream>>>(x, c0_0, c0_1, out, ws);
}

// Round 4
// 6373.709 us; speedup vs baseline: 3.4349x; 1.5890x over previous
//
#include <hip/hip_runtime.h>

// ---------------------------------------------------------------------------
// Persistent weight-stationary LSTM, bf16 MFMA, fence-free low-traffic sync.
// T=1024 B=64 C=256 H=512, 2 layers, fp32 in/out.
//  - 256 blocks x 256 threads, 1 block/CU; blocks 0..127 = layer0 (step t),
//    128..255 = layer1 (step t-1) -> one grid barrier per tick.
//  - Cross-block data via sc0/sc1 (LLC-coherent) ops; no fences in the loop.
//  - h-fragment loads: inline-asm global_load_dwordx4 sc0 sc1 with immediate
//    offsets; all 16/32 destinations forced live -> ONE LLC round per tick
//    (was 4-6 register-starved serialized rounds at VGPR=104).
//  - Barrier: block b stores monotone tick in slot[b]. ONLY block0/wave0
//    scans the 256 slots (64 lanes x 4), publishes gen to 4 spread lines;
//    other blocks poll gen with tid0 only. Poll LLC traffic ~1000x lower
//    than R3's all-block-wave0 scan (which saturated the fabric).
//  - Critical path per tick: h-store -> vmcnt(0) -> syncthreads -> flag.
//    out/fin stores + x[t+1] prefetch in the barrier-wait shadow.
//  - mfma_f32_16x16x32_bf16: A[m=lane&15][k=quad*8+j], B(N,K)[n=lane&15][k=quad*8+j],
//    D[m=quad*4+reg][n=lane&15]  (guide-verified mapping, m90/m97 convention)
// ---------------------------------------------------------------------------

#define TT 1024
#define BB 64
#define CC 256
#define HH 512
#define Y_ELEMS (TT * BB * HH)
#define S_ELEMS (BB * HH)

typedef __attribute__((ext_vector_type(8))) short bf16x8;
typedef __attribute__((ext_vector_type(4))) float f32x4;
typedef unsigned int u32;
typedef unsigned short u16;
typedef unsigned long long u64;

// ---- ws layout (bytes) ----
#define WS_BAR 0           // 256 slots * 128B (one per block)
#define WS_GEN 32768       // 4 gen lines * 128B
#define WS_BSUM0 36864     // 2048 f32
#define WS_BSUM1 45056     // 2048 f32
#define WS_H0 53248        // 2 * 32768 u16 (h0 ping-pong, bf16)
#define WS_H1 184320       // 2 * 32768 u16
#define WS_WPK0 315392     // 128*24*64*8 bf16  (layer0 packed W)
#define WS_WPK1 3461120    // 128*32*64*8 bf16  (layer1 packed W)
// end 7655424 (~7.66 MB)

__device__ __forceinline__ u16 f2b_rne(float f) {
    u32 u = __float_as_uint(f);
    return (u16)((u + 0x7FFFu + ((u >> 16) & 1u)) >> 16);
}
__device__ __forceinline__ u16 f2b_fast(float f) {  // round-half-up, 2 ops
    return (u16)((__float_as_uint(f) + 0x8000u) >> 16);
}
__device__ __forceinline__ float sigf(float z) { return 1.0f / (1.0f + __expf(-z)); }
__device__ __forceinline__ float tanh_f(float z) { return 2.0f / (1.0f + __expf(-2.0f * z)) - 1.0f; }

__device__ __forceinline__ bf16x8 pack8(float4 a, float4 b) {
    union { u16 u[8]; bf16x8 v; } r;
    r.u[0] = f2b_fast(a.x); r.u[1] = f2b_fast(a.y); r.u[2] = f2b_fast(a.z); r.u[3] = f2b_fast(a.w);
    r.u[4] = f2b_fast(b.x); r.u[5] = f2b_fast(b.y); r.u[6] = f2b_fast(b.z); r.u[7] = f2b_fast(b.w);
    return r.v;
}

__device__ __forceinline__ u32 ld_u32_sc(const u32* p) {
    return __hip_atomic_load(p, __ATOMIC_RELAXED, __HIP_MEMORY_SCOPE_AGENT);
}
__device__ __forceinline__ void st_u32_sc(u32* p, u32 v) {
    __hip_atomic_store(p, v, __ATOMIC_RELAXED, __HIP_MEMORY_SCOPE_AGENT);
}
__device__ __forceinline__ void st_h_sc(u16* p, u16 v) {
    __hip_atomic_store(p, v, __ATOMIC_RELAXED, __HIP_MEMORY_SCOPE_AGENT);
}

// N cache-bypassing 16B loads, base + compile-time offsets, all issued
// back-to-back with forced-live destinations -> one LLC latency round.
template <int I, int N>
struct FragLd {
    static __device__ __forceinline__ void go(f32x4* d, const u16* p) {
        asm volatile("global_load_dwordx4 %0, %1, off offset:%c2 sc0 sc1"
                     : "=&v"(d[I]) : "v"(p), "n"(I * 64) : "memory");
        FragLd<I + 1, N>::go(d, p);
    }
};
template <int N>
struct FragLd<N, N> {
    static __device__ __forceinline__ void go(f32x4*, const u16*) {}
};

// ---- init: zero barrier region, bsum = bih+bhh, h buffers <- bf16(initial h) ----
__global__ void k_init(const float* __restrict__ bih0, const float* __restrict__ bhh0,
                       const float* __restrict__ bih1, const float* __restrict__ bhh1,
                       const float* __restrict__ h00, const float* __restrict__ h01,
                       unsigned char* __restrict__ ws) {
    u32* bar = (u32*)(ws + WS_BAR);
    float* bs0 = (float*)(ws + WS_BSUM0);
    float* bs1 = (float*)(ws + WS_BSUM1);
    u16* h0 = (u16*)(ws + WS_H0);
    u16* h1 = (u16*)(ws + WS_H1);
    int t = blockIdx.x * 256 + threadIdx.x;  // 32768 threads
    if (t < 9216) bar[t] = 0u;               // slots + gen region (36864 B)
    if (t < 2048) { bs0[t] = bih0[t] + bhh0[t]; bs1[t] = bih1[t] + bhh1[t]; }
    if (t < S_ELEMS) { h0[t] = f2b_rne(h00[t]); h1[t] = f2b_rne(h01[t]); }
}

// ---- weight pack: fp32 [4H,K] -> bf16 B-frag order wpk[bidL][kt][lane][8] ----
// rows permuted: n-index (lane&15) = gg*4+jj  <->  W row = gg*512 + bidL*4 + jj
__global__ void k_wprep(const float* __restrict__ Wih0, const float* __restrict__ Whh0,
                        const float* __restrict__ Wih1, const float* __restrict__ Whh1,
                        unsigned char* __restrict__ ws) {
    u16* wpk0 = (u16*)(ws + WS_WPK0);
    u16* wpk1 = (u16*)(ws + WS_WPK1);
    int u = blockIdx.x * 256 + threadIdx.x;  // 458752 threads
    const float* s;
    u16* d;
    if (u < 128 * 24 * 64) {  // layer0: 8 x-tiles (K=256) + 16 h-tiles (K=512)
        int bidL = u / (24 * 64);
        int kt = (u >> 6) % 24;
        int lane = u & 63;
        int n = lane & 15, quad = lane >> 4;
        int row = (n >> 2) * 512 + bidL * 4 + (n & 3);
        int k = kt * 32 + quad * 8;
        s = (k < 256) ? (Wih0 + (size_t)row * 256 + k) : (Whh0 + (size_t)row * 512 + (k - 256));
        d = wpk0 + (size_t)((bidL * 24 + kt) * 64 + lane) * 8;
    } else {  // layer1: 16 y0-tiles + 16 h1-tiles (K=1024)
        int v = u - 128 * 24 * 64;
        int bidL = v / (32 * 64);
        int kt = (v >> 6) % 32;
        int lane = v & 63;
        int n = lane & 15, quad = lane >> 4;
        int row = (n >> 2) * 512 + bidL * 4 + (n & 3);
        int k = kt * 32 + quad * 8;
        s = (k < 512) ? (Wih1 + (size_t)row * 512 + k) : (Whh1 + (size_t)row * 512 + (k - 512));
        d = wpk1 + (size_t)((bidL * 32 + kt) * 64 + lane) * 8;
    }
    #pragma unroll
    for (int i = 0; i < 8; ++i) d[i] = f2b_rne(s[i]);
}

// ---- the persistent tick loop, templated on layer ----
template <int LAYER>
__device__ void run_ticks(const float* __restrict__ x, const float* __restrict__ c0,
                          float* __restrict__ out, unsigned char* __restrict__ ws, int bidL) {
    constexpr int NKT = (LAYER == 0) ? 24 : 32;
    u32* slots = (u32*)(ws + WS_BAR);
    u32* gen = (u32*)(ws + WS_GEN);
    const float* bs = (const float*)(ws + (LAYER == 0 ? WS_BSUM0 : WS_BSUM1));
    u16* h0b[2] = { (u16*)(ws + WS_H0), (u16*)(ws + WS_H0) + S_ELEMS };
    u16* h1b[2] = { (u16*)(ws + WS_H1), (u16*)(ws + WS_H1) + S_ELEMS };
    const u16* wpk = (const u16*)(ws + (LAYER == 0 ? WS_WPK0 : WS_WPK1));

    const int tid = threadIdx.x, lane = tid & 63, wave = tid >> 6;
    const int r16 = lane & 15, quad = lane >> 4, q8 = quad * 8;
    const int gg = r16 >> 2, jj = r16 & 3;
    const int b0 = wave * 16;
    const int col = bidL * 4 + jj;            // h column this lane finalizes
    const int myb = b0 + quad * 4 + gg;       // batch this lane finalizes
    const int sl0 = (quad << 4) | (0 << 2) | jj;
    const int sl1 = (quad << 4) | (1 << 2) | jj;
    const int sl2 = (quad << 4) | (2 << 2) | jj;
    const int sl3 = (quad << 4) | (3 << 2) | jj;

    // biases (hoisted), c state in register for the whole run
    const float bi = bs[0 * HH + col], bf_ = bs[1 * HH + col];
    const float bg = bs[2 * HH + col], bo = bs[3 * HH + col];
    float c = c0[myb * HH + col];

    // weight fragments: loaded once; reloads (if rematerialized) hit L1/L2
    // since nothing invalidates caches anymore.
    f32x4 wf[NKT];
    {
        const u16* wp = wpk + (size_t)(bidL * NKT * 64 + lane) * 8;
        #pragma unroll
        for (int kt = 0; kt < NKT; ++kt) wf[kt] = *(const f32x4*)(wp + (size_t)kt * 64 * 8);
        #pragma unroll
        for (int kt = 0; kt < NKT; ++kt) asm volatile("" : "+v"(wf[kt]));
    }

    // layer0: x prefetch registers (t=0 issued before the loop)
    float4 xf0[8], xf1[8];
    if (LAYER == 0) {
        const float* xp = x + (size_t)(b0 + r16) * CC + q8;
        #pragma unroll
        for (int kt = 0; kt < 8; ++kt) {
            xf0[kt] = *(const float4*)(xp + kt * 32);
            xf1[kt] = *(const float4*)(xp + kt * 32 + 4);
        }
    }

    for (int i = 0; i <= TT; ++i) {
        const bool active = (LAYER == 0) ? (i < TT) : (i >= 1);
        const int t = (LAYER == 0) ? i : i - 1;
        float h = 0.f;
        if (active) {
            f32x4 a0 = {0.f,0.f,0.f,0.f}, a1 = {0.f,0.f,0.f,0.f};
            f32x4 a2 = {0.f,0.f,0.f,0.f}, a3 = {0.f,0.f,0.f,0.f};
            if (LAYER == 0) {
                // issue the 16 recurrent h fragments: one LLC round
                f32x4 afr[16];
                const u16* hp = h0b[t & 1] + (size_t)(b0 + r16) * HH + q8;
                FragLd<0, 16>::go(afr, hp);
                // x projection from prefetched registers overlaps the h-load flight
                #pragma unroll
                for (int kt = 0; kt < 8; ++kt) {
                    bf16x8 a = pack8(xf0[kt], xf1[kt]);
                    bf16x8 wv = __builtin_bit_cast(bf16x8, wf[kt]);
                    f32x4& dst = (kt & 2) ? ((kt & 1) ? a3 : a2) : ((kt & 1) ? a1 : a0);
                    dst = __builtin_amdgcn_mfma_f32_16x16x32_bf16(a, wv, dst, 0, 0, 0);
                }
                asm volatile("s_waitcnt vmcnt(0)" ::: "memory");
                __builtin_amdgcn_sched_barrier(0);
                #pragma unroll
                for (int kt = 0; kt < 16; ++kt) {
                    bf16x8 av = __builtin_bit_cast(bf16x8, afr[kt]);
                    bf16x8 wv = __builtin_bit_cast(bf16x8, wf[8 + kt]);
                    f32x4& dst = (kt & 2) ? ((kt & 1) ? a3 : a2) : ((kt & 1) ? a1 : a0);
                    dst = __builtin_amdgcn_mfma_f32_16x16x32_bf16(av, wv, dst, 0, 0, 0);
                }
            } else {
                // y0[t] = h0 written at tick t (parity (t+1)&1); h1 prev at t&1
                f32x4 afr[32];
                const u16* pa = h0b[(t + 1) & 1] + (size_t)(b0 + r16) * HH + q8;
                const u16* pb = h1b[t & 1] + (size_t)(b0 + r16) * HH + q8;
                FragLd<0, 16>::go(afr, pa);
                FragLd<0, 16>::go(afr + 16, pb);
                asm volatile("s_waitcnt vmcnt(0)" ::: "memory");
                __builtin_amdgcn_sched_barrier(0);
                #pragma unroll
                for (int kt = 0; kt < 32; ++kt) {
                    bf16x8 av = __builtin_bit_cast(bf16x8, afr[kt]);
                    bf16x8 wv = __builtin_bit_cast(bf16x8, wf[kt]);
                    f32x4& dst = (kt & 2) ? ((kt & 1) ? a3 : a2) : ((kt & 1) ? a1 : a0);
                    dst = __builtin_amdgcn_mfma_f32_16x16x32_bf16(av, wv, dst, 0, 0, 0);
                }
            }
            f32x4 acc = (a0 + a1) + (a2 + a3);

            // gather the 4 gates for (myb, col): lanes sharing (quad,jj), gg = gate
            float gi = 0.f, gf = 0.f, gc = 0.f, go = 0.f;
            #pragma unroll
            for (int r = 0; r < 4; ++r) {
                float v0 = __shfl(acc[r], sl0, 64);
                float v1 = __shfl(acc[r], sl1, 64);
                float v2 = __shfl(acc[r], sl2, 64);
                float v3 = __shfl(acc[r], sl3, 64);
                if (r == gg) { gi = v0; gf = v1; gc = v2; go = v3; }
            }
            gi = sigf(gi + bi);
            gf = sigf(gf + bf_);
            gc = tanh_f(gc + bg);
            go = sigf(go + bo);
            c = gf * c + gi * gc;
            h = go * tanh_f(c);

            u16* hw = (LAYER == 0) ? h0b[(t + 1) & 1] : h1b[(t + 1) & 1];
            st_h_sc(&hw[myb * HH + col], f2b_rne(h));       // the only pre-flag store
        }
        // ---- barrier arrival: drain h store, then raise flag ----
        if (i < TT) {
            asm volatile("s_waitcnt vmcnt(0)" ::: "memory");
            __syncthreads();   // all waves of this block drained
            if (tid == 0)
                st_u32_sc(&slots[(u32)blockIdx.x * 32], (u32)(i + 1));
        }
        // ---- shadow work while flags propagate / peers finish ----
        if (active) {
            if (LAYER == 1) out[(size_t)t * S_ELEMS + myb * HH + col] = h;
            if (t == TT - 1) {
                float* fin = out + Y_ELEMS + (LAYER == 0 ? 0 : 2) * S_ELEMS;
                fin[myb * HH + col] = h;
                fin[S_ELEMS + myb * HH + col] = c;
            }
        }
        if (LAYER == 0 && i + 1 < TT) {      // prefetch x[t+1] into registers
            const float* xp = x + ((size_t)(i + 1) * BB + b0 + r16) * CC + q8;
            #pragma unroll
            for (int kt = 0; kt < 8; ++kt) {
                xf0[kt] = *(const float4*)(xp + kt * 32);
                xf1[kt] = *(const float4*)(xp + kt * 32 + 4);
            }
        }
        // ---- barrier completion: aggregator (block 0) or gen-poll (others) ----
        if (i < TT) {
            const u32 tgt = (u32)(i + 1);
            if (blockIdx.x == 0) {
                if (tid < 64) {  // wave 0 scans all 256 slots, 4 per lane
                    const u32* p0 = slots + ((u32)tid * 4 + 0) * 32;
                    const u32* p1 = slots + ((u32)tid * 4 + 1) * 32;
                    const u32* p2 = slots + ((u32)tid * 4 + 2) * 32;
                    const u32* p3 = slots + ((u32)tid * 4 + 3) * 32;
                    u32 m;
                    do {
                        u32 va = ld_u32_sc(p0);
                        u32 vb = ld_u32_sc(p1);
                        u32 vc = ld_u32_sc(p2);
                        u32 vd = ld_u32_sc(p3);
                        m = min(min(va, vb), min(vc, vd));
                    } while (m < tgt);
                }
                __syncthreads();
                if (tid == 0) {
                    #pragma unroll
                    for (int k2 = 0; k2 < 4; ++k2) st_u32_sc(gen + k2 * 32, tgt);
                }
            } else {
                if (tid == 0) {
                    const u32* gp = gen + ((u32)blockIdx.x & 3) * 32;
                    while (ld_u32_sc(gp) < tgt) { }
                }
                __syncthreads();
            }
        }
    }
}

__global__ __launch_bounds__(256) __attribute__((amdgpu_waves_per_eu(1, 1)))
void k_lstm(const float* __restrict__ x,
            const float* __restrict__ c00,
            const float* __restrict__ c01,
            float* __restrict__ out,
            unsigned char* __restrict__ ws) {
    const int bid = blockIdx.x;
    if (bid < 128) run_ticks<0>(x, c00, out, ws, bid);
    else           run_ticks<1>(x, c01, out, ws, bid - 128);
}

extern "C" void kernel_launch(void* const* d_in, const int* in_sizes, int n_in,
                              void* d_out, int out_size, void* d_ws, size_t ws_size,
                              hipStream_t stream) {
    const float* x    = (const float*)d_in[0];
    const float* h0_0 = (const float*)d_in[1];
    const float* c0_0 = (const float*)d_in[2];
    const float* h0_1 = (const float*)d_in[3];
    const float* c0_1 = (const float*)d_in[4];
    const float* Wih0 = (const float*)d_in[5];
    const float* Whh0 = (const float*)d_in[6];
    const float* bih0 = (const float*)d_in[7];
    const float* bhh0 = (const float*)d_in[8];
    const float* Wih1 = (const float*)d_in[9];
    const float* Whh1 = (const float*)d_in[10];
    const float* bih1 = (const float*)d_in[11];
    const float* bhh1 = (const float*)d_in[12];
    float* out = (float*)d_out;
    unsigned char* ws = (unsigned char*)d_ws;

    k_init<<<128, 256, 0, stream>>>(bih0, bhh0, bih1, bhh1, h0_0, h0_1, ws);
    k_wprep<<<1792, 256, 0, stream>>>(Wih0, Whh0, Wih1, Whh1, ws);
    k_lstm<<<256, 256, 0, stream>>>(x, c0_0, c0_1, out, ws);
}